// Round 7
// baseline (185.303 us; speedup 1.0000x reference)
//
#include <hip/hip_runtime.h>
#include <cstdint>

#define GH 10
#define GW 10

// Four lanes per sample (dense 64B-line loads, whole sample in registers).
// VALU-trimmed vs round 5: float-abs coordinate math, funnel-shift S_T,
// 2-way de-replicated flood fill, 4-way de-replicated argmin.
__global__ __launch_bounds__(256, 4) void custom_loss_kernel(
    const float* __restrict__ result,
    const int* __restrict__ points,
    float* __restrict__ out,
    int B)
{
    const int tid = blockIdx.x * blockDim.x + threadIdx.x;
    const int s = tid >> 2;      // sample
    const int q = tid & 3;       // quad lane
    float loss = 0.f;
    if (s < B) {
        const float* __restrict__ r = result + (size_t)s * 100;
        const int4 p = ((const int4*)points)[s];
        const int p0y = p.x, p0x = p.y, p1y = p.z, p1x = p.w;
        const int dy0 = abs(p0y - p1y), dx0 = abs(p0x - p1x);
        const int base0 = dy0 + dx0;
        const int idx0 = p0y * GW + p0x;
        const int idx1 = p1y * GW + p1x;
        const float rs = r[idx0];          // quad-uniform -> broadcast
        const float re = r[idx1];
        const float p0yf = (float)p0y, p0xf = (float)p0x;
        const float p1yf = (float)p1y, p1xf = (float)p1x;
        const float dy0f = (float)dy0, dx0f = (float)dx0;
        const float basef = (float)base0;

        // ---- dense coalesced quad loads (16 full lines per wave-inst) ----
        float4 v4[7];
#pragma unroll
        for (int i = 0; i < 6; ++i) v4[i] = ((const float4*)r)[4 * i + q];
        v4[6] = make_float4(0.f, 0.f, 0.f, 0.f);
        if (q == 0) v4[6] = ((const float4*)r)[24];   // floats 96..99

        // ---- pass 1: float-abs math (|a-b| = sub + add w/ abs modifiers) ----
        float sum_p = 0.f, scA = 0.f, scB = 0.f, box_p = 0.f;
        uint64_t mlo = 0, mhi = 0;
#pragma unroll
        for (int i = 0; i < 7; ++i) {
            const int kbase = (i < 6) ? 4 * (4 * i + q) : (96 + 4 * q);
            const int y0 = (kbase * 205) >> 11;       // kbase/10, kbase<1024
            const int x0 = kbase - 10 * y0;           // x0 is always even
            const float y0f = (float)y0, x0f = (float)x0;
            const float sy0 = fabsf(y0f - p0yf) + fabsf(y0f - p1yf);
            const float sy1 = fabsf(y0f + 1.f - p0yf) + fabsf(y0f + 1.f - p1yf);
            const bool wrap = (x0 == 8);              // only even-x0 straddle
            const float vv[4] = {v4[i].x, v4[i].y, v4[i].z, v4[i].w};
            uint32_t nib = 0;
#pragma unroll
            for (int j = 0; j < 4; ++j) {
                const bool w = wrap && (j >= 2);      // cell rolls to next row
                const float xf = x0f + (w ? (float)(j - 10) : (float)j);
                const float syj = w ? sy1 : sy0;
                const float v = vv[j];
                const float sx = fabsf(xf - p0xf) + fabsf(xf - p1xf);
                sum_p += v;
                scA = fmaf(syj, v, scA);              // sum v*sy
                scB = fmaf(sx, v, scB);               // sum v*sx
                box_p += ((sx == dx0f) & (syj == dy0f)) ? v : 0.f;  // exact ints
                // jnp.round half-to-even: for v in [0,1), round==1 <=> v>0.5
                nib |= (v > 0.5f) ? (1u << j) : 0u;
            }
            // place nibble at bit kbase of the 100-bit board (50+50 split)
            const uint64_t n64 = (uint64_t)nib;
            const int shhi = (kbase >= 50) ? (kbase - 50) : 0;
            mlo |= (kbase <= 44) ? (n64 << kbase)
                                 : ((kbase == 48) ? ((n64 & 3ull) << 48) : 0);
            mhi |= (kbase >= 52) ? (n64 << shhi)
                                 : ((kbase == 48) ? (n64 >> 2) : 0);
        }
        // quad merges
        sum_p += __shfl_xor(sum_p, 1); sum_p += __shfl_xor(sum_p, 2);
        scA   += __shfl_xor(scA, 1);   scA   += __shfl_xor(scA, 2);
        scB   += __shfl_xor(scB, 1);   scB   += __shfl_xor(scB, 2);
        box_p += __shfl_xor(box_p, 1); box_p += __shfl_xor(box_p, 2);
        mlo |= (uint64_t)__shfl_xor((unsigned long long)mlo, 1);
        mlo |= (uint64_t)__shfl_xor((unsigned long long)mlo, 2);
        mhi |= (uint64_t)__shfl_xor((unsigned long long)mhi, 1);
        mhi |= (uint64_t)__shfl_xor((unsigned long long)mhi, 2);
        const float sum_all = sum_p, boxSum = box_p;
        // sum v*delta = sum v*(sy+sx) - base*sum_all   (all integer-exact coeffs)
        const float sc = fmaf(-basef, sum_all, scA + scB);

        // ---- flood fill, 2-way split: lanes {0,1} iterate lo, {2,3} hi ----
        const uint64_t M50 = (1ull << 50) - 1;
        const uint64_t C0  = 0x10040100401ull;        // col-0 bit of 5 rows
        const uint64_t NC0 = M50 & ~C0;               // clear col0 after <<1
        const uint64_t NC9 = M50 & ~(C0 << 9);        // clear col9 after >>1
        const int half = q >> 1;
        const uint64_t mw = half ? mhi : mlo;
        uint64_t c = 0;
        if (half == 0 && idx0 < 50)  c = 1ull << idx0;
        if (half == 1 && idx0 >= 50) c = 1ull << (idx0 - 50);
#pragma unroll 1
        for (int it = 0; it < GH + GW; ++it) {        // cap 20 = reference
            const uint64_t ho = c | ((c << 1) & NC0) | ((c >> 1) & NC9);
            const uint64_t hoth = (uint64_t)__shfl_xor((unsigned long long)ho, 2);
            const uint64_t inc = half ? (hoth >> 40) : ((hoth & 0x3FFull) << 40);
            const uint64_t n = ((ho | (ho << 10) | (ho >> 10) | inc) & mw) | c;
            int ch = (n != c) ? 1 : 0;
            ch += __shfl_xor(ch, 2);                  // uniform across quad
            c = n;
            if (!ch) break;                           // global fixpoint only
        }
        int Kh = __popcll(c);
        const int K = Kh + __shfl_xor(Kh, 2);
        const uint64_t coth = (uint64_t)__shfl_xor((unsigned long long)c, 2);
        const uint64_t clo = half ? coth : c;
        const uint64_t chi = half ? c : coth;
        const uint32_t cl32 = (uint32_t)clo;

        // ---- S_T: funnel-shift + stride-10 nibble gather (4 cells/float4) ----
        // in_cl[y][x] = cluster bit (x*10+y); for a float4 at (y0,x0) the
        // transposed bits sit at s0+{0,10,20,30}, s0 = x0*10+y0 (<=30 -> low32).
        float st_p = 0.f;
#pragma unroll
        for (int i = 0; i < 7; ++i) {
            const int kbase = (i < 6) ? 4 * (4 * i + q) : (96 + 4 * q);
            const int y0 = (kbase * 205) >> 11;
            const int x0 = kbase - 10 * y0;
            const int s0 = x0 * 10 + y0;
            const uint64_t tA = (clo >> (s0 & 63)) | (chi << ((50 - s0) & 63));
            const uint64_t tB = chi >> ((s0 - 50) & 63);
            const uint32_t tl = (uint32_t)((s0 < 50) ? tA : tB);
            uint32_t nib = (tl & 1u) | ((tl >> 9) & 2u) |
                           ((tl >> 18) & 4u) | ((tl >> 27) & 8u);
            if (x0 == 8) {   // straddle: cells j=2,3 are (y0+1, 0/1) -> bits y0+1, y0+11
                const uint32_t b2 = (cl32 >> (y0 + 1)) & 1u;
                const uint32_t b3 = (cl32 >> (y0 + 11)) & 1u;
                nib = (nib & 3u) | (b2 << 2) | (b3 << 3);
            }
            const float vv[4] = {v4[i].x, v4[i].y, v4[i].z, v4[i].w};
#pragma unroll
            for (int j = 0; j < 4; ++j)
                st_p += (nib & (1u << j)) ? vv[j] : 0.f;
        }
        st_p += __shfl_xor(st_p, 1); st_p += __shfl_xor(st_p, 2);
        const float S_T = st_p;

        // ---- argmin, 4-way split: lane q owns rows {q, q+4, q+8} ----
        // key = (d<<7)|flatidx reproduces first-flat-index tie-break exactly.
        int bestkey = 0x7FFFFFFF;
#pragma unroll
        for (int k = 0; k < 3; ++k) {
            const int y = q + 4 * k;
            if (y < GH) {
                const uint32_t rb = (uint32_t)(((y < 5) ? (clo >> (10 * y))
                                                        : (chi >> (10 * (y - 5)))) & 0x3FFull);
                const uint32_t left  = rb & ((2u << p1x) - 1);
                const uint32_t right = rb >> p1x;
                const int dl = left  ? (p1x - (31 - __builtin_clz(left))) : 1000;
                const int dr = right ? __builtin_ctz(right) : 1000;
                int dx, xx;
                if (dl <= dr) { dx = dl; xx = p1x - dl; }      // tie -> smaller col
                else          { dx = dr; xx = p1x + dr; }
                const int key = ((abs(y - p1y) + dx) << 7) | (y * GW + xx);
                if (rb && key < bestkey) bestkey = key;
            }
        }
        bestkey = min(bestkey, __shfl_xor(bestkey, 1));
        bestkey = min(bestkey, __shfl_xor(bestkey, 2));
        const int bestd = bestkey >> 7;
        const int bidx = bestkey & 127;

        // ---- epilogue (replicated across quad; only q==0 contributes) ----
        const bool better = bestd < base0;
        const int ny = better ? bidx / 10 : p0y;
        const int nx = better ? bidx % 10 : p0x;
        const int gap = min(base0, bestd);

        int by = ny, bx = nx, bg = gap;
        const int oy = p1y - ny, ox = p1x - nx;
        auto upd = [&](bool cond, int cy, int cx) {
            const int d = abs(cy - p1y) + abs(cx - p1x);
            if (cond && (d < bg)) { by = cy; bx = cx; bg = d; }
        };
        upd(ox < 0,                     ny,     nx - 1);
        upd((ox < 0) && (ny != 0),      ny - 1, nx - 1);
        upd((ox < 0) && (ny != GH - 1), ny + 1, nx - 1);
        upd(ox > 0,                     ny,     nx + 1);
        upd((ox > 0) && (ny != 0),      ny - 1, nx + 1);
        upd((ox > 0) && (ny != GH - 1), ny + 1, nx + 1);
        upd(oy < 0,                     ny - 1, nx);
        upd(oy > 0,                     ny + 1, nx);
        const int ncy = min(max(by, 0), GH - 1);
        const int ncx = min(max(bx, 0), GW - 1);
        const float rn = r[ncy * GW + ncx];   // quad-uniform dependent load

        const float csf = (float)K;
        const float nboxf = (float)((dy0 + 1) * (dx0 + 1));
        const float loss_start = (2.f - (rs + re)) * 1000.f;
        const float lon = 5.f * csf + 15.f * sum_all - 20.f * S_T;
        const float single_cell = 0.5f * sc + 20.f * (nboxf - boxSum);
        const float cpen = 12.f * csf * S_T;
        const float gap_pen = (float)gap * 300.f * (1.f - rn);
        loss = loss_start + lon + single_cell + cpen + gap_pen;
        if (q != 0) loss = 0.f;               // one contribution per sample
    }

    // ---- block reduction: wave shuffle -> LDS -> one atomic per block ----
#pragma unroll
    for (int off = 32; off > 0; off >>= 1)
        loss += __shfl_down(loss, off);
    __shared__ float wsum[4];
    const int lane = threadIdx.x & 63;
    const int wid = threadIdx.x >> 6;
    if (lane == 0) wsum[wid] = loss;
    __syncthreads();
    if (threadIdx.x == 0)
        atomicAdd(out, wsum[0] + wsum[1] + wsum[2] + wsum[3]);
}

extern "C" void kernel_launch(void* const* d_in, const int* in_sizes, int n_in,
                              void* d_out, int out_size, void* d_ws, size_t ws_size,
                              hipStream_t stream)
{
    const float* result = (const float*)d_in[0];
    const int* points   = (const int*)d_in[1];
    float* out = (float*)d_out;
    const int B = in_sizes[0] / 100;
    hipMemsetAsync(out, 0, sizeof(float), stream);   // harness poisons d_out with 0xAA
    const int block = 256;
    const int grid = (4 * B + block - 1) / block;    // 4 lanes per sample
    custom_loss_kernel<<<grid, block, 0, stream>>>(result, points, out, B);
}